// Round 6
// baseline (165.080 us; speedup 1.0000x reference)
//
#include <hip/hip_runtime.h>
#include <hip/hip_bf16.h>

typedef __attribute__((ext_vector_type(8))) short short8;
typedef __attribute__((ext_vector_type(4))) float f32x4;

#define B_SZ 32
#define T_SZ 4096
#define H_SZ 512
#define NROWS (B_SZ * T_SZ)   // 131072

// packed fp32x2 -> bf16x2 (RNE), single v_cvt_pk_bf16_f32: a->low16, b->high16
static __device__ __forceinline__ unsigned int pack2(float a, float b) {
  unsigned int r;
  asm("v_cvt_pk_bf16_f32 %0, %1, %2" : "=v"(r) : "v"(a), "v"(b));
  return r;
}

// branch-free tanh, exact saturation at +/-inf: 1 - 2/(e^{2x}+1)
static __device__ __forceinline__ float fast_tanh(float x) {
  float e = __expf(2.0f * x);
  return 1.0f - 2.0f / (e + 1.0f);
}

// ---- W fp32 (512x512) -> bf16 in MFMA-fragment order ----
// fragment s = grow*64 + kt*4 + kslot; holds W[grow][kt*32 + kslot*8 .. +8]
// dst uint4 index = nb*1024 + kt*64 + (kslot*16 + g); a 16-g chunk = 16 KB contiguous
__global__ __launch_bounds__(256) void prep_w_kernel(
    const float* __restrict__ W, uint4* __restrict__ Wfrag) {
  int s = blockIdx.x * 256 + threadIdx.x;   // 0..32767
  int grow  = s >> 6;
  int kt    = (s >> 2) & 15;
  int kslot = s & 3;
  const float4* Wf4 = reinterpret_cast<const float4*>(W);
  float4 lo = Wf4[grow * 128 + kt * 8 + kslot * 2];
  float4 hi = Wf4[grow * 128 + kt * 8 + kslot * 2 + 1];
  uint4 u;
  u.x = pack2(lo.x, lo.y); u.y = pack2(lo.z, lo.w);
  u.z = pack2(hi.x, hi.y); u.w = pack2(hi.z, hi.w);
  int nb = grow >> 4, g = grow & 15;
  Wfrag[nb * 1024 + kt * 64 + kslot * 16 + g] = u;
}

// ---- scores[row] = sum_g v[g] * tanh( X[row,:] . W[g,:] ) ----
// 512 thr = 8 waves, wave owns 16 rows (M=16, afrag 64 VGPR) -> block M=128.
// Small footprint (~105 VGPR, 32 KB LDS) + launch_bounds(512,4) targets
// 4 waves/SIMD from 2 INDEPENDENT blocks — TLP hides the barrier drain that
// capped r2-r5 at 2 waves/SIMD lockstep.
__global__ __launch_bounds__(512, 4) void score_kernel(
    const float* __restrict__ X, const uint4* __restrict__ Wfrag,
    const float* __restrict__ v, float* __restrict__ scores) {
  __shared__ unsigned char WsB[2][16384];

  const int tid   = threadIdx.x;
  const int lane  = tid & 63;
  const int wave  = tid >> 6;
  const int frow  = lane & 15;   // A: m row / B: g col
  const int kslot = lane >> 4;
  const size_t rowbase = (size_t)blockIdx.x * 128;
  const size_t arow = rowbase + wave * 16 + frow;

  // stage chunk c into buffer b: 16 KB linear, 2 KB (2 loads) per wave
  #define STAGE(c, b)                                                           \
    {                                                                           \
      const char* src = (const char*)Wfrag + (size_t)(c) * 16384 +              \
                        wave * 2048 + lane * 16;                                \
      unsigned char* dst = &WsB[b][wave * 2048];                                \
      _Pragma("unroll")                                                         \
      for (int i = 0; i < 2; ++i)                                               \
        __builtin_amdgcn_global_load_lds((const unsigned int*)(src + i * 1024), \
                                         (unsigned int*)(dst + i * 1024), 16, 0, 0); \
    }

  STAGE(0, 0);   // latency hides under A-load/convert

  // A fragments: X[arow][kt*32 + kslot*8 .. +8] for kt=0..15, bf16-packed (64 VGPR)
  short8 afrag[16];
  {
    const float4* xr = reinterpret_cast<const float4*>(X + arow * H_SZ);
    #pragma unroll
    for (int kt = 0; kt < 16; ++kt) {
      float4 lo = xr[kt * 8 + kslot * 2];
      float4 hi = xr[kt * 8 + kslot * 2 + 1];
      union { uint4 u; short8 s; } cv;
      cv.u.x = pack2(lo.x, lo.y); cv.u.y = pack2(lo.z, lo.w);
      cv.u.z = pack2(hi.x, hi.y); cv.u.w = pack2(hi.z, hi.w);
      afrag[kt] = cv.s;
    }
  }
  __syncthreads();   // chunk 0 staged, A ready

  float red[4] = {0.f, 0.f, 0.f, 0.f};

  for (int ch = 0; ch < 32; ++ch) {
    if (ch < 31) STAGE(ch + 1, (ch + 1) & 1);   // prefetch into other buffer
    float vg = v[ch * 16 + frow];

    // 2 independent accumulator chains (kt parity)
    f32x4 acc0 = {0.f, 0.f, 0.f, 0.f};
    f32x4 acc1 = {0.f, 0.f, 0.f, 0.f};
    const unsigned char* bb = &WsB[ch & 1][lane * 16];
    #pragma unroll
    for (int kt = 0; kt < 16; kt += 2) {
      short8 b0 = *reinterpret_cast<const short8*>(bb + kt * 1024);        // linear, conflict-free
      short8 b1 = *reinterpret_cast<const short8*>(bb + (kt + 1) * 1024);
      acc0 = __builtin_amdgcn_mfma_f32_16x16x32_bf16(afrag[kt],     b0, acc0, 0, 0, 0);
      acc1 = __builtin_amdgcn_mfma_f32_16x16x32_bf16(afrag[kt + 1], b1, acc1, 0, 0, 0);
    }
    // D[m][n]: n = frow (g), m = kslot*4 + reg
    #pragma unroll
    for (int r = 0; r < 4; ++r)
      red[r] = fmaf(vg, fast_tanh(acc0[r] + acc1[r]), red[r]);

    __syncthreads();   // stage drained; next buffer ready; reads of cur done
  }
  #undef STAGE

  // reduce over the 16 g-lanes (frow) within each kslot group
  #pragma unroll
  for (int r = 0; r < 4; ++r) {
    #pragma unroll
    for (int d = 1; d < 16; d <<= 1)
      red[r] += __shfl_xor(red[r], d);
  }
  if (frow == 0) {
    float* sp = scores + rowbase + wave * 16 + kslot * 4;
    sp[0] = red[0]; sp[1] = red[1]; sp[2] = red[2]; sp[3] = red[3];
  }
}

// ---- per-b softmax stats; rewrites scores in place with unnormalized exp ----
__global__ __launch_bounds__(256) void softmax_kernel(
    float* __restrict__ scores, float* __restrict__ denom) {
  const int b = blockIdx.x;
  float* s = scores + b * T_SZ;
  const int tid = threadIdx.x;
  __shared__ float redm[4], reds[4];

  float m = -1e30f;
  for (int t = tid; t < T_SZ; t += 256) m = fmaxf(m, s[t]);
  #pragma unroll
  for (int d = 1; d < 64; d <<= 1) m = fmaxf(m, __shfl_xor(m, d));
  if ((tid & 63) == 0) redm[tid >> 6] = m;
  __syncthreads();
  m = fmaxf(fmaxf(redm[0], redm[1]), fmaxf(redm[2], redm[3]));

  float sum = 0.f;
  for (int t = tid; t < T_SZ; t += 256) {
    float u = __expf(s[t] - m);
    s[t] = u;
    sum += u;
  }
  #pragma unroll
  for (int d = 1; d < 64; d <<= 1) sum += __shfl_xor(sum, d);
  if ((tid & 63) == 0) reds[tid >> 6] = sum;
  __syncthreads();
  if (tid == 0) denom[b] = reds[0] + reds[1] + reds[2] + reds[3];
}

// ---- partial[b][ch][h] = sum_{t in chunk} u_t * x[b,t,h] ----
__global__ __launch_bounds__(256) void wsum_kernel(
    const float* __restrict__ X, const float* __restrict__ u,
    float* __restrict__ partial) {
  const int ch = blockIdx.x;   // 32 chunks of 128 t
  const int b  = blockIdx.y;   // 32
  const float* xb = X + ((size_t)b * T_SZ + ch * 128) * H_SZ;
  const float* ub = u + b * T_SZ + ch * 128;
  const int h2 = threadIdx.x;  // float2 index
  float ax = 0.f, ay = 0.f;
  for (int tt = 0; tt < 128; ++tt) {
    float w = ub[tt];
    float2 xv = reinterpret_cast<const float2*>(xb + (size_t)tt * H_SZ)[h2];
    ax = fmaf(w, xv.x, ax);
    ay = fmaf(w, xv.y, ay);
  }
  float2 r; r.x = ax; r.y = ay;
  reinterpret_cast<float2*>(partial + ((size_t)b * 32 + ch) * H_SZ)[h2] = r;
}

// ---- out[b][h] = (1/denom_b) * sum_ch partial[b][ch][h] ----
__global__ __launch_bounds__(256) void finalize_kernel(
    const float* __restrict__ partial, const float* __restrict__ denom,
    float* __restrict__ out) {
  const int b = blockIdx.x;
  const float inv = 1.0f / denom[b];
  for (int h = threadIdx.x; h < H_SZ; h += 256) {
    float s = 0.f;
    #pragma unroll
    for (int c = 0; c < 32; ++c) s += partial[((size_t)b * 32 + c) * H_SZ + h];
    out[b * H_SZ + h] = s * inv;
  }
}

extern "C" void kernel_launch(void* const* d_in, const int* in_sizes, int n_in,
                              void* d_out, int out_size, void* d_ws, size_t ws_size,
                              hipStream_t stream) {
  const float* X = (const float*)d_in[0];   // (32,4096,512)
  const float* W = (const float*)d_in[1];   // (512,512)
  const float* v = (const float*)d_in[2];   // (512,)
  float* out = (float*)d_out;               // (32,512) fp32
  unsigned char* ws = (unsigned char*)d_ws;

  uint4* Wfrag   = (uint4*)(ws);                        // 512 KB
  float* scores  = (float*)(ws + (512u << 10));         // 512 KB (becomes u)
  float* denom   = (float*)(ws + (1024u << 10));        // 128 B
  float* partial = (float*)(ws + (1024u << 10) + 512);  // 2 MB

  prep_w_kernel<<<128, 256, 0, stream>>>(W, Wfrag);
  score_kernel<<<NROWS / 128, 512, 0, stream>>>(X, Wfrag, v, scores);
  softmax_kernel<<<B_SZ, 256, 0, stream>>>(scores, denom);
  dim3 g(32, B_SZ);
  wsum_kernel<<<g, 256, 0, stream>>>(X, scores, partial);
  finalize_kernel<<<B_SZ, 256, 0, stream>>>(partial, denom, out);
}

// Round 7
// 154.065 us; speedup vs baseline: 1.0715x; 1.0715x over previous
//
#include <hip/hip_runtime.h>
#include <hip/hip_bf16.h>

typedef __attribute__((ext_vector_type(8))) short short8;
typedef __attribute__((ext_vector_type(4))) float f32x4;

#define B_SZ 32
#define T_SZ 4096
#define H_SZ 512
#define NROWS (B_SZ * T_SZ)   // 131072

// packed fp32x2 -> bf16x2 (RNE), single v_cvt_pk_bf16_f32: a->low16, b->high16
static __device__ __forceinline__ unsigned int pack2(float a, float b) {
  unsigned int r;
  asm("v_cvt_pk_bf16_f32 %0, %1, %2" : "=v"(r) : "v"(a), "v"(b));
  return r;
}

// branch-free tanh, exact saturation at +/-inf: 1 - 2/(e^{2x}+1)
static __device__ __forceinline__ float fast_tanh(float x) {
  float e = __expf(2.0f * x);
  return 1.0f - 2.0f / (e + 1.0f);
}

// ---- W fp32 (512x512) -> bf16 in MFMA-fragment order ----
// fragment s = grow*64 + kt*4 + kslot; holds W[grow][kt*32 + kslot*8 .. +8]
// dst uint4 index = nb*1024 + kt*64 + (kslot*16 + g); a 16-g chunk = 16 KB contiguous
__global__ __launch_bounds__(256) void prep_w_kernel(
    const float* __restrict__ W, uint4* __restrict__ Wfrag) {
  int s = blockIdx.x * 256 + threadIdx.x;   // 0..32767
  int grow  = s >> 6;
  int kt    = (s >> 2) & 15;
  int kslot = s & 3;
  const float4* Wf4 = reinterpret_cast<const float4*>(W);
  float4 lo = Wf4[grow * 128 + kt * 8 + kslot * 2];
  float4 hi = Wf4[grow * 128 + kt * 8 + kslot * 2 + 1];
  uint4 u;
  u.x = pack2(lo.x, lo.y); u.y = pack2(lo.z, lo.w);
  u.z = pack2(hi.x, hi.y); u.w = pack2(hi.z, hi.w);
  int nb = grow >> 4, g = grow & 15;
  Wfrag[nb * 1024 + kt * 64 + kslot * 16 + g] = u;
}

// ---- fused: scores (MFMA) + block-local softmax partials + partial num ----
// 512 thr = 8 waves, wave owns 16 rows -> block M=128, grid 1024.
// Outputs per block: num[512] = sum_t exp(s_t - m_loc) X[t,:], (m_loc, den_loc).
__global__ __launch_bounds__(512, 4) void score_fused_kernel(
    const float* __restrict__ X, const uint4* __restrict__ Wfrag,
    const float* __restrict__ v,
    float* __restrict__ num, float2* __restrict__ md) {
  __shared__ unsigned char WsB[2][16384];
  __shared__ float sLDS[128];
  __shared__ float pLDS[128];
  __shared__ float mred[2], dred[2];

  const int tid   = threadIdx.x;
  const int lane  = tid & 63;
  const int wave  = tid >> 6;
  const int frow  = lane & 15;   // A: m row / B: g col
  const int kslot = lane >> 4;
  const size_t rowbase = (size_t)blockIdx.x * 128;
  const size_t arow = rowbase + wave * 16 + frow;

  // stage chunk c into buffer b: 16 KB linear, 2 KB (2 loads) per wave
  #define STAGE(c, b)                                                           \
    {                                                                           \
      const char* src = (const char*)Wfrag + (size_t)(c) * 16384 +              \
                        wave * 2048 + lane * 16;                                \
      unsigned char* dst = &WsB[b][wave * 2048];                                \
      _Pragma("unroll")                                                         \
      for (int i = 0; i < 2; ++i)                                               \
        __builtin_amdgcn_global_load_lds((const unsigned int*)(src + i * 1024), \
                                         (unsigned int*)(dst + i * 1024), 16, 0, 0); \
    }

  STAGE(0, 0);   // latency hides under A-load/convert

  // A fragments: X[arow][kt*32 + kslot*8 .. +8] for kt=0..15, bf16-packed (64 VGPR)
  short8 afrag[16];
  {
    const float4* xr = reinterpret_cast<const float4*>(X + arow * H_SZ);
    #pragma unroll
    for (int kt = 0; kt < 16; ++kt) {
      float4 lo = xr[kt * 8 + kslot * 2];
      float4 hi = xr[kt * 8 + kslot * 2 + 1];
      union { uint4 u; short8 s; } cv;
      cv.u.x = pack2(lo.x, lo.y); cv.u.y = pack2(lo.z, lo.w);
      cv.u.z = pack2(hi.x, hi.y); cv.u.w = pack2(hi.z, hi.w);
      afrag[kt] = cv.s;
    }
  }
  __syncthreads();   // chunk 0 staged, A ready

  float red[4] = {0.f, 0.f, 0.f, 0.f};

  for (int ch = 0; ch < 32; ++ch) {
    // v load FIRST (oldest vmem): the epilogue's wait on vg then leaves the
    // two younger stage loads in flight instead of draining them.
    float vg = v[ch * 16 + frow];
    if (ch < 31) STAGE(ch + 1, (ch + 1) & 1);   // prefetch into other buffer

    // 2 independent accumulator chains (kt parity)
    f32x4 acc0 = {0.f, 0.f, 0.f, 0.f};
    f32x4 acc1 = {0.f, 0.f, 0.f, 0.f};
    const unsigned char* bb = &WsB[ch & 1][lane * 16];
    #pragma unroll
    for (int kt = 0; kt < 16; kt += 2) {
      short8 b0 = *reinterpret_cast<const short8*>(bb + kt * 1024);        // linear, conflict-free
      short8 b1 = *reinterpret_cast<const short8*>(bb + (kt + 1) * 1024);
      acc0 = __builtin_amdgcn_mfma_f32_16x16x32_bf16(afrag[kt],     b0, acc0, 0, 0, 0);
      acc1 = __builtin_amdgcn_mfma_f32_16x16x32_bf16(afrag[kt + 1], b1, acc1, 0, 0, 0);
    }
    // D[m][n]: n = frow (g), m = kslot*4 + reg
    #pragma unroll
    for (int r = 0; r < 4; ++r)
      red[r] = fmaf(vg, fast_tanh(acc0[r] + acc1[r]), red[r]);

    __syncthreads();   // stage drained; next buffer ready; reads of cur done
  }
  #undef STAGE

  // reduce over the 16 g-lanes (frow) within each kslot group
  #pragma unroll
  for (int r = 0; r < 4; ++r) {
    #pragma unroll
    for (int d = 1; d < 16; d <<= 1)
      red[r] += __shfl_xor(red[r], d);
  }
  if (frow == 0) {
    float* sp = sLDS + wave * 16 + kslot * 4;
    sp[0] = red[0]; sp[1] = red[1]; sp[2] = red[2]; sp[3] = red[3];
  }
  __syncthreads();

  // ---- block-local softmax stats over the 128 rows (waves 0,1) ----
  if (tid < 128) {
    float s = sLDS[tid];
    float m = s;
    #pragma unroll
    for (int d = 1; d < 64; d <<= 1) m = fmaxf(m, __shfl_xor(m, d));
    if ((tid & 63) == 0) mred[tid >> 6] = m;
  }
  __syncthreads();
  const float m_loc = fmaxf(mred[0], mred[1]);
  if (tid < 128) {
    float p = __expf(sLDS[tid] - m_loc);
    pLDS[tid] = p;
    #pragma unroll
    for (int d = 1; d < 64; d <<= 1) p += __shfl_xor(p, d);
    if ((tid & 63) == 0) dred[tid >> 6] = p;
  }
  __syncthreads();

  // ---- partial numerator: thread owns h = tid; X tile is L2/L3-hot ----
  float a = 0.f;
  const float* xb = X + rowbase * H_SZ + tid;
  #pragma unroll 8
  for (int t = 0; t < 128; ++t)
    a = fmaf(pLDS[t], xb[(size_t)t * H_SZ], a);
  num[(size_t)blockIdx.x * H_SZ + tid] = a;
  if (tid == 0) {
    float2 r; r.x = m_loc; r.y = dred[0] + dred[1];
    md[blockIdx.x] = r;
  }
}

// ---- combine 32 block-partials per batch with global-max rescale ----
__global__ __launch_bounds__(512) void combine_kernel(
    const float* __restrict__ num, const float2* __restrict__ md,
    float* __restrict__ out) {
  const int b = blockIdx.x;   // 32
  const int h = threadIdx.x;  // 512
  float M = -1e30f;
  #pragma unroll
  for (int c = 0; c < 32; ++c) M = fmaxf(M, md[b * 32 + c].x);
  float den = 0.f, acc = 0.f;
  #pragma unroll 4
  for (int c = 0; c < 32; ++c) {
    float2 m2 = md[b * 32 + c];
    float w = __expf(m2.x - M);
    den += w * m2.y;
    acc = fmaf(w, num[(size_t)(b * 32 + c) * H_SZ + h], acc);
  }
  out[b * H_SZ + h] = acc / den;
}

extern "C" void kernel_launch(void* const* d_in, const int* in_sizes, int n_in,
                              void* d_out, int out_size, void* d_ws, size_t ws_size,
                              hipStream_t stream) {
  const float* X = (const float*)d_in[0];   // (32,4096,512)
  const float* W = (const float*)d_in[1];   // (512,512)
  const float* v = (const float*)d_in[2];   // (512,)
  float* out = (float*)d_out;               // (32,512) fp32
  unsigned char* ws = (unsigned char*)d_ws;

  uint4* Wfrag = (uint4*)(ws);                          // 512 KB
  float* num   = (float*)(ws + (512u << 10));           // 1024*512*4 = 2 MB
  float2* md   = (float2*)(ws + (512u << 10) + (2u << 20));  // 8 KB

  prep_w_kernel<<<128, 256, 0, stream>>>(W, Wfrag);
  score_fused_kernel<<<NROWS / 128, 512, 0, stream>>>(X, Wfrag, v, num, md);
  combine_kernel<<<B_SZ, 512, 0, stream>>>(num, md, out);
}